// Round 1
// baseline (307.510 us; speedup 1.0000x reference)
//
#include <hip/hip_runtime.h>
#include <math.h>

// Problem constants (match reference setup_inputs)
constexpr int S = 4096;   // sequence length
constexpr int D = 1024;   // d_model
constexpr int B = 4;      // batch
constexpr int F = 64;     // num frequencies

constexpr int DB = 256;   // d-columns per block (== blockDim.x)
constexpr int SB = 32;    // s-rows per block

__global__ __launch_bounds__(256, 2)
void WaveEncoder_46359876993378_kernel(const int* __restrict__ tokens,
                                       const void* __restrict__ t_ptr,
                                       const float* __restrict__ emb,
                                       const float* __restrict__ amp,
                                       const float* __restrict__ freq,
                                       float* __restrict__ out)
{
    __shared__ float2 trig[SB][F];   // (cos, sin) per (s_local, m) : 16 KiB
    __shared__ int    tok[SB][B];    // token ids for this s-tile

    const int tid = threadIdx.x;
    const int d   = blockIdx.x * DB + tid;
    const int s0  = blockIdx.y * SB;

    const float TWO_PI = 6.28318530717958647692f;

    // ---- decode t robustly (int32 / int64-low-word / float32-bits) ----
    int ti = *(const int*)t_ptr;
    float t = (ti > -1048576 && ti < 1048576) ? (float)ti : __int_as_float(ti);

    // ---- A column into registers: a[m] = amplitudes[m, d] ----
    float a[F];
    #pragma unroll
    for (int m = 0; m < F; ++m) a[m] = amp[m * D + d];

    // ---- trig table for this block's 32 s-values (2048 sincos total) ----
    for (int i = tid; i < SB * F; i += DB) {
        const int sl = i >> 6;          // / F
        const int m  = i & (F - 1);     // % F
        const float k     = TWO_PI * (float)(s0 + sl) * (1.0f / (float)S);
        const float phase = k - TWO_PI * freq[m] * t;
        float sv, cv;
        sincosf(phase, &sv, &cv);
        trig[sl][m] = make_float2(cv, sv);
    }
    // ---- token ids for (s_local, b) ----
    if (tid < SB * B) {
        const int sl = tid >> 2;
        const int b  = tid & 3;
        tok[sl][b] = tokens[b * S + s0 + sl];
    }
    __syncthreads();

    const size_t plane = (size_t)B * S * D;   // offset of wave_imag
    const size_t SD    = (size_t)S * D;

    for (int sl = 0; sl < SB; ++sl) {
        // issue the 4 gather loads first — their latency hides under the FMA loop
        const int r0 = tok[sl][0], r1 = tok[sl][1], r2 = tok[sl][2], r3 = tok[sl][3];
        const float e0 = emb[(size_t)r0 * D + d];
        const float e1 = emb[(size_t)r1 * D + d];
        const float e2 = emb[(size_t)r2 * D + d];
        const float e3 = emb[(size_t)r3 * D + d];

        // coef accumulation: 128 FMAs, 4 independent chains for ILP
        float cr0 = 0.f, cr1 = 0.f, ci0 = 0.f, ci1 = 0.f;
        #pragma unroll
        for (int m = 0; m < F; m += 2) {
            const float2 w0 = trig[sl][m];
            const float2 w1 = trig[sl][m + 1];
            cr0 = fmaf(a[m],     w0.x, cr0);
            ci0 = fmaf(a[m],     w0.y, ci0);
            cr1 = fmaf(a[m + 1], w1.x, cr1);
            ci1 = fmaf(a[m + 1], w1.y, ci1);
        }
        const float cr = cr0 + cr1;
        const float ci = ci0 + ci1;

        const size_t o = (size_t)(s0 + sl) * D + d;
        // wave_real
        out[o         ] = cr * e0;
        out[o +     SD] = cr * e1;
        out[o + 2 * SD] = cr * e2;
        out[o + 3 * SD] = cr * e3;
        // wave_imag
        out[plane + o         ] = ci * e0;
        out[plane + o +     SD] = ci * e1;
        out[plane + o + 2 * SD] = ci * e2;
        out[plane + o + 3 * SD] = ci * e3;
    }
}

extern "C" void kernel_launch(void* const* d_in, const int* in_sizes, int n_in,
                              void* d_out, int out_size, void* d_ws, size_t ws_size,
                              hipStream_t stream) {
    const int*   tokens = (const int*)  d_in[0];
    const void*  t_ptr  =               d_in[1];
    const float* emb    = (const float*)d_in[2];
    const float* amp    = (const float*)d_in[3];
    const float* freq   = (const float*)d_in[4];
    float*       out    = (float*)d_out;

    dim3 grid(D / DB, S / SB);   // (4, 128) = 512 blocks
    dim3 block(DB);
    WaveEncoder_46359876993378_kernel<<<grid, block, 0, stream>>>(
        tokens, t_ptr, emb, amp, freq, out);
}

// Round 2
// 305.213 us; speedup vs baseline: 1.0075x; 1.0075x over previous
//
#include <hip/hip_runtime.h>
#include <math.h>

// Problem constants (match reference setup_inputs)
constexpr int S = 4096;   // sequence length
constexpr int D = 1024;   // d_model
constexpr int B = 4;      // batch
constexpr int F = 64;     // num frequencies

constexpr float TWO_PI = 6.28318530717958647692f;

// ---------------------------------------------------------------------------
// Kernel 1: P[d] = sum_m A[m,d] * cos(w_m t);  Q[d] = sum_m A[m,d] * sin(w_m t)
// ws[0..D)   = P
// ws[D..2D)  = Q
// ---------------------------------------------------------------------------
__global__ __launch_bounds__(256)
void we_coef_kernel(const float* __restrict__ amp,
                    const float* __restrict__ freq,
                    const void*  __restrict__ t_ptr,
                    float* __restrict__ ws)
{
    __shared__ float cm[F], sm[F];

    const int tid = threadIdx.x;
    const int d   = blockIdx.x * 256 + tid;

    // decode t robustly (int32 / int64-low-word / float32-bits)
    int ti = *(const int*)t_ptr;
    float t = (ti > -1048576 && ti < 1048576) ? (float)ti : __int_as_float(ti);

    if (tid < F) {
        float sv, cv;
        sincosf(TWO_PI * freq[tid] * t, &sv, &cv);
        cm[tid] = cv;
        sm[tid] = sv;
    }
    __syncthreads();

    float P = 0.f, Q = 0.f;
    #pragma unroll
    for (int m = 0; m < F; ++m) {
        const float a = amp[m * D + d];
        P = fmaf(a, cm[m], P);
        Q = fmaf(a, sm[m], Q);
    }
    ws[d]     = P;
    ws[D + d] = Q;
}

// ---------------------------------------------------------------------------
// Kernel 2: pure streaming gather-multiply-store.
//   real[b,s,d] = (cos k_s * P[d] + sin k_s * Q[d]) * emb[tok[b,s], d]
//   imag[b,s,d] = (sin k_s * P[d] - cos k_s * Q[d]) * emb[tok[b,s], d]
// One block = 256 threads = D/4 float4 columns; SB s-rows per block.
// ---------------------------------------------------------------------------
constexpr int SB = 4;     // s-rows per block
constexpr int D4 = D / 4; // 256 float4 columns

__global__ __launch_bounds__(256, 4)
void we_main_kernel(const int* __restrict__ tokens,
                    const float* __restrict__ emb,
                    const float* __restrict__ ws,
                    float* __restrict__ out)
{
    const int tid = threadIdx.x;
    const int s0  = blockIdx.x * SB;

    const float4* __restrict__ emb4 = (const float4*)emb;
    const float4* __restrict__ P4p  = (const float4*)ws;
    const float4* __restrict__ Q4p  = (const float4*)(ws + D);
    float4* __restrict__ out4       = (float4*)out;

    const float4 P = P4p[tid];
    const float4 Q = Q4p[tid];

    const size_t plane4 = (size_t)B * S * D4;   // imag-plane offset in float4s

    for (int i = 0; i < SB; ++i) {
        const int s = s0 + i;

        // token ids (wave-uniform -> scalar loads); issue gathers first
        const int r0 = tokens[0 * S + s];
        const int r1 = tokens[1 * S + s];
        const int r2 = tokens[2 * S + s];
        const int r3 = tokens[3 * S + s];
        const float4 e0 = emb4[(size_t)r0 * D4 + tid];
        const float4 e1 = emb4[(size_t)r1 * D4 + tid];
        const float4 e2 = emb4[(size_t)r2 * D4 + tid];
        const float4 e3 = emb4[(size_t)r3 * D4 + tid];

        // per-row trig (uniform across lanes; cheap)
        float sn, cs;
        sincosf(TWO_PI * (float)s * (1.0f / (float)S), &sn, &cs);

        float4 rc, ic;
        rc.x = fmaf(cs, P.x, sn * Q.x);  ic.x = fmaf(sn, P.x, -cs * Q.x);
        rc.y = fmaf(cs, P.y, sn * Q.y);  ic.y = fmaf(sn, P.y, -cs * Q.y);
        rc.z = fmaf(cs, P.z, sn * Q.z);  ic.z = fmaf(sn, P.z, -cs * Q.z);
        rc.w = fmaf(cs, P.w, sn * Q.w);  ic.w = fmaf(sn, P.w, -cs * Q.w);

        #define MULW(e, rv, iv) \
            rv.x = rc.x * e.x; rv.y = rc.y * e.y; rv.z = rc.z * e.z; rv.w = rc.w * e.w; \
            iv.x = ic.x * e.x; iv.y = ic.y * e.y; iv.z = ic.z * e.z; iv.w = ic.w * e.w;

        float4 r, im;
        const size_t o0 = ((size_t)(0 * S + s)) * D4 + tid;
        const size_t o1 = ((size_t)(1 * S + s)) * D4 + tid;
        const size_t o2 = ((size_t)(2 * S + s)) * D4 + tid;
        const size_t o3 = ((size_t)(3 * S + s)) * D4 + tid;

        MULW(e0, r, im); out4[o0] = r; out4[plane4 + o0] = im;
        MULW(e1, r, im); out4[o1] = r; out4[plane4 + o1] = im;
        MULW(e2, r, im); out4[o2] = r; out4[plane4 + o2] = im;
        MULW(e3, r, im); out4[o3] = r; out4[plane4 + o3] = im;
        #undef MULW
    }
}

extern "C" void kernel_launch(void* const* d_in, const int* in_sizes, int n_in,
                              void* d_out, int out_size, void* d_ws, size_t ws_size,
                              hipStream_t stream) {
    const int*   tokens = (const int*)  d_in[0];
    const void*  t_ptr  =               d_in[1];
    const float* emb    = (const float*)d_in[2];
    const float* amp    = (const float*)d_in[3];
    const float* freq   = (const float*)d_in[4];
    float*       out    = (float*)d_out;
    float*       ws     = (float*)d_ws;

    we_coef_kernel<<<dim3(D / 256), dim3(256), 0, stream>>>(amp, freq, t_ptr, ws);
    we_main_kernel<<<dim3(S / SB), dim3(256), 0, stream>>>(tokens, emb, ws, out);
}